// Round 7
// baseline (228.426 us; speedup 1.0000x reference)
//
#include <hip/hip_runtime.h>
#include <hip/hip_fp16.h>

#define NN 100000
#define NE 1600000
#define NG 256
#define NPB 32            // nodes per block-pass in layer kernel
#define LAYER_GRID 2048
#define SIDX 1280         // staged csr entries per pass (mean 512, +34 sigma)

// binned CSR build
#define BSH 9                         // bucket = dst >> 9 (512 nodes/bucket)
#define NBKT ((NN + 511) / 512)       // 196
#define CAP 9216                      // per-bucket capacity (mean 8163, +11.7 sigma)
#define TILE_A 4096
#define NBLK_A ((NE + TILE_A - 1) / TILE_A)   // 391

typedef _Float16 f16x8 __attribute__((ext_vector_type(8)));
typedef float f32x4 __attribute__((ext_vector_type(4)));

__device__ __forceinline__ uint2 f4_to_h16(float4 o) {
    __half2 lo = __floats2half2_rn(o.x, o.y);
    __half2 hi = __floats2half2_rn(o.z, o.w);
    uint2 u;
    u.x = *(unsigned int*)&lo;
    u.y = *(unsigned int*)&hi;
    return u;
}

// ---------------- fp32 -> fp16 convert (for x) ----------------
__global__ __launch_bounds__(256) void cvt_kernel(const float* __restrict__ in,
                                                  __half* __restrict__ out) {
    const int i = blockIdx.x * 256 + threadIdx.x;   // one float4 per thread
    const int n4 = NN * 64 / 4;                     // 1.6M
    if (i < n4) {
        float4 v = ((const float4*)in)[i];
        ((uint2*)out)[i] = f4_to_h16(v);
    }
}

// ---------------- weight prep: 4 mats fp32 [k][n] -> fp16 [n][k] ----------------
__global__ __launch_bounds__(256) void wprep_kernel(const float* __restrict__ Wa,
                                                    const float* __restrict__ Wc,
                                                    const float* __restrict__ Wb,
                                                    const float* __restrict__ Wd,
                                                    __half* __restrict__ out) {
    const int i = blockIdx.x * 256 + threadIdx.x;   // 0..16383
    if (i < 16384) {
        const int m = i >> 12;
        const int e = i & 4095;
        const int n = e >> 6, k = e & 63;
        const float* W = (m == 0) ? Wa : (m == 1) ? Wc : (m == 2) ? Wb : Wd;
        out[m * 4096 + n * 64 + k] = __float2half(W[k * 64 + n]);
    }
}

// ---------------- binned CSR build ----------------
__global__ __launch_bounds__(256) void initcur_kernel(int* __restrict__ gcur) {
    int t = threadIdx.x;
    if (t < NBKT) gcur[t] = t * CAP;
}

__global__ __launch_bounds__(256) void binA_kernel(const int* __restrict__ src,
                                                   const int* __restrict__ dst,
                                                   int* __restrict__ gcur,
                                                   unsigned int* __restrict__ binned)
{
    __shared__ int hist[NBKT];
    __shared__ int cnt2[NBKT];
    __shared__ int lexcl[NBKT];
    __shared__ int base[NBKT];
    __shared__ int s[256];
    __shared__ unsigned int buf[TILE_A];
    __shared__ unsigned char bkt8[TILE_A];

    const int t = threadIdx.x;
    const int e0 = blockIdx.x * TILE_A;
    const int nedge = min(TILE_A, NE - e0);

    if (t < NBKT) { hist[t] = 0; cnt2[t] = 0; }
    __syncthreads();

    for (int j = t; j < nedge; j += 256)
        atomicAdd(&hist[dst[e0 + j] >> BSH], 1);
    __syncthreads();

    s[t] = (t < NBKT) ? hist[t] : 0;
    __syncthreads();
    for (int off = 1; off < 256; off <<= 1) {
        int u = (t >= off) ? s[t - off] : 0;
        __syncthreads();
        s[t] += u;
        __syncthreads();
    }
    if (t < NBKT) {
        lexcl[t] = s[t] - hist[t];
        if (hist[t] > 0) base[t] = atomicAdd(&gcur[t], hist[t]);
    }
    __syncthreads();

    for (int j = t; j < nedge; j += 256) {
        const int d = dst[e0 + j];
        const int sv = src[e0 + j];
        const int b = d >> BSH;
        const int r = atomicAdd(&cnt2[b], 1);
        const int idx = lexcl[b] + r;
        buf[idx] = ((unsigned int)sv << BSH) | (unsigned int)(d & 511);
        bkt8[idx] = (unsigned char)b;
    }
    __syncthreads();

    for (int j = t; j < nedge; j += 256) {
        const int b = bkt8[j];
        binned[base[b] + (j - lexcl[b])] = buf[j];
    }
}

__global__ __launch_bounds__(256) void bscan_kernel(const int* __restrict__ gcur,
                                                    int* __restrict__ bbase,
                                                    int* __restrict__ rs)
{
    __shared__ int s[256];
    const int t = threadIdx.x;
    const int sz = (t < NBKT) ? (gcur[t] - t * CAP) : 0;
    s[t] = sz;
    __syncthreads();
    for (int off = 1; off < 256; off <<= 1) {
        int u = (t >= off) ? s[t - off] : 0;
        __syncthreads();
        s[t] += u;
        __syncthreads();
    }
    if (t < NBKT) bbase[t] = s[t] - sz;
    if (t == 0) rs[NN] = NE;
}

__global__ __launch_bounds__(256) void binB_kernel(const unsigned int* __restrict__ binned,
                                                   const int* __restrict__ gcur,
                                                   const int* __restrict__ bbase,
                                                   int* __restrict__ csr,
                                                   int* __restrict__ rs)
{
    __shared__ int cnt[512];
    __shared__ int excl[512];
    __shared__ int cnt2[512];
    __shared__ int psum[256];
    __shared__ unsigned int buf[CAP];

    const int b = blockIdx.x;
    const int t = threadIdx.x;
    const int sz = gcur[b] - b * CAP;
    const int gb = bbase[b];
    const unsigned int* bp = binned + b * CAP;

    cnt[t] = 0; cnt[t + 256] = 0;
    cnt2[t] = 0; cnt2[t + 256] = 0;
    __syncthreads();

    for (int j = t; j < sz; j += 256) {
        const unsigned int v = bp[j];
        buf[j] = v;
        atomicAdd(&cnt[v & 511], 1);
    }
    __syncthreads();

    const int c0 = cnt[2 * t], c1 = cnt[2 * t + 1];
    psum[t] = c0 + c1;
    __syncthreads();
    for (int off = 1; off < 256; off <<= 1) {
        int u = (t >= off) ? psum[t - off] : 0;
        __syncthreads();
        psum[t] += u;
        __syncthreads();
    }
    const int pe = psum[t] - (c0 + c1);
    excl[2 * t] = pe;
    excl[2 * t + 1] = pe + c0;
    __syncthreads();

    const int node0 = b << BSH;
    for (int l = t; l < 512; l += 256) {
        const int node = node0 + l;
        if (node < NN) rs[node] = gb + excl[l];
    }

    for (int j = t; j < sz; j += 256) {
        const unsigned int v = buf[j];
        const int l = v & 511;
        const int r = atomicAdd(&cnt2[l], 1);
        csr[gb + excl[l] + r] = (int)(v >> BSH);
    }
}

// ---------------- fused GNN layer: MFMA dense + gathered agg ----------------
// out = relu( h@Wa+ba + agg(h)@Wc+bc + (h@Wb+bb)*(h@Wd+bd) )
// 256 thr = 4 waves, pass = 32 nodes. Weights live in registers (fp16
// pre-transposed by wprep). LDS: sX1/sX2 (padded 72) + staged csr slice.
__device__ __forceinline__ void accu8(float* a8, uint4 u) {
    const __half2* hp = (const __half2*)&u;
    #pragma unroll
    for (int q = 0; q < 4; ++q) {
        float2 f = __half22float2(hp[q]);
        a8[2 * q] += f.x; a8[2 * q + 1] += f.y;
    }
}

__global__ __launch_bounds__(256) void layer_kernel(
    const __half* __restrict__ h_in, __half* __restrict__ h_out,
    const int* __restrict__ csr, const int* __restrict__ rs,
    const __half* __restrict__ wt,
    const float* __restrict__ ba, const float* __restrict__ bc,
    const float* __restrict__ bb, const float* __restrict__ bd)
{
    __shared__ _Float16 sX1[NPB][72];
    __shared__ _Float16 sX2[NPB][72];
    __shared__ int sIdx[SIDX];

    const int tid = threadIdx.x;

    // gather indexing: 8 threads per node
    const int slot = tid >> 3;      // 0..31
    const int fg8  = tid & 7;       // 16B feature chunk

    // mfma indexing
    const int w   = tid >> 6;       // N-tile 0..3
    const int l   = tid & 63;
    const int lr  = l & 15;
    const int kh  = l >> 4;
    const int col = w * 16 + lr;

    // per-block one-time: B-fragments (4 mats x 2 k-halves) into registers
    const _Float16* wtf = (const _Float16*)wt;
    f16x8 wrA0 = *(const f16x8*)&wtf[0 * 4096 + col * 64 + 0 * 32 + kh * 8];
    f16x8 wrA1 = *(const f16x8*)&wtf[0 * 4096 + col * 64 + 1 * 32 + kh * 8];
    f16x8 wrC0 = *(const f16x8*)&wtf[1 * 4096 + col * 64 + 0 * 32 + kh * 8];
    f16x8 wrC1 = *(const f16x8*)&wtf[1 * 4096 + col * 64 + 1 * 32 + kh * 8];
    f16x8 wrB0 = *(const f16x8*)&wtf[2 * 4096 + col * 64 + 0 * 32 + kh * 8];
    f16x8 wrB1 = *(const f16x8*)&wtf[2 * 4096 + col * 64 + 1 * 32 + kh * 8];
    f16x8 wrD0 = *(const f16x8*)&wtf[3 * 4096 + col * 64 + 0 * 32 + kh * 8];
    f16x8 wrD1 = *(const f16x8*)&wtf[3 * 4096 + col * 64 + 1 * 32 + kh * 8];
    const float bA = ba[col], bC = bc[col], bB = bb[col], bD = bd[col];

    const int npass = (NN + NPB - 1) / NPB;
    for (int g = blockIdx.x; g < npass; g += gridDim.x) {
        const int node0 = g * NPB;
        const int e0 = rs[node0];
        const int eN = rs[min(node0 + NPB, NN)];
        const int staged = min(eN - e0, SIDX);

        __syncthreads();   // prev pass fully consumed (sX MFMA reads, sIdx reads)
        for (int j = tid; j < staged; j += 256) sIdx[j] = csr[e0 + j];
        __syncthreads();

        // ---- gather phase ----
        const int node = node0 + slot;
        uint4 hreg = make_uint4(0u, 0u, 0u, 0u);
        float a8[8] = {0.f, 0.f, 0.f, 0.f, 0.f, 0.f, 0.f, 0.f};
        if (node < NN) {
            hreg = *(const uint4*)(h_in + node * 64 + fg8 * 8);
            const int rsn = rs[node];
            const int ne  = rs[node + 1] - rsn;
            const int le  = rsn - e0;
            for (int q = 0; q < ne; q += 8) {
                const int rem = ne - q;
                const int jb = le + q;
                auto gi = [&](int i) {
                    const int jr = jb + i;
                    return (jr < staged) ? sIdx[jr] : csr[e0 + jr];
                };
                const int s0 = gi(0);
                const int s1 = rem > 1 ? gi(1) : s0;
                const int s2 = rem > 2 ? gi(2) : s0;
                const int s3 = rem > 3 ? gi(3) : s0;
                const int s4 = rem > 4 ? gi(4) : s0;
                const int s5 = rem > 5 ? gi(5) : s0;
                const int s6 = rem > 6 ? gi(6) : s0;
                const int s7 = rem > 7 ? gi(7) : s0;
                const uint4 u0 = *(const uint4*)(h_in + s0 * 64 + fg8 * 8);
                const uint4 u1 = *(const uint4*)(h_in + s1 * 64 + fg8 * 8);
                const uint4 u2 = *(const uint4*)(h_in + s2 * 64 + fg8 * 8);
                const uint4 u3 = *(const uint4*)(h_in + s3 * 64 + fg8 * 8);
                const uint4 u4 = *(const uint4*)(h_in + s4 * 64 + fg8 * 8);
                const uint4 u5 = *(const uint4*)(h_in + s5 * 64 + fg8 * 8);
                const uint4 u6 = *(const uint4*)(h_in + s6 * 64 + fg8 * 8);
                const uint4 u7 = *(const uint4*)(h_in + s7 * 64 + fg8 * 8);
                accu8(a8, u0);
                if (rem > 1) accu8(a8, u1);
                if (rem > 2) accu8(a8, u2);
                if (rem > 3) accu8(a8, u3);
                if (rem > 4) accu8(a8, u4);
                if (rem > 5) accu8(a8, u5);
                if (rem > 6) accu8(a8, u6);
                if (rem > 7) accu8(a8, u7);
            }
        }

        // ---- stage into LDS (prev-pass readers passed barrier above) ----
        *(uint4*)&sX1[slot][fg8 * 8] = hreg;
        union { _Float16 h[8]; uint4 u; } cv;
        #pragma unroll
        for (int j = 0; j < 8; ++j) cv.h[j] = (_Float16)a8[j];
        *(uint4*)&sX2[slot][fg8 * 8] = cv.u;
        __syncthreads();

        // ---- MFMA phase: wave w = N-tile w; M-tiles rows 0-15 and 16-31 ----
        f32x4 accA1 = {0.f,0.f,0.f,0.f}, accC1 = {0.f,0.f,0.f,0.f};
        f32x4 accB1 = {0.f,0.f,0.f,0.f}, accD1 = {0.f,0.f,0.f,0.f};
        f32x4 accA2 = {0.f,0.f,0.f,0.f}, accC2 = {0.f,0.f,0.f,0.f};
        f32x4 accB2 = {0.f,0.f,0.f,0.f}, accD2 = {0.f,0.f,0.f,0.f};
        #pragma unroll
        for (int kk = 0; kk < 2; ++kk) {
            const int ko = kk * 32 + kh * 8;
            const f16x8 wa = kk ? wrA1 : wrA0;
            const f16x8 wc = kk ? wrC1 : wrC0;
            const f16x8 wb = kk ? wrB1 : wrB0;
            const f16x8 wd = kk ? wrD1 : wrD0;
            const f16x8 a1r0 = *(const f16x8*)&sX1[lr][ko];
            const f16x8 a2r0 = *(const f16x8*)&sX2[lr][ko];
            const f16x8 a1r1 = *(const f16x8*)&sX1[16 + lr][ko];
            const f16x8 a2r1 = *(const f16x8*)&sX2[16 + lr][ko];
            accA1 = __builtin_amdgcn_mfma_f32_16x16x32_f16(a1r0, wa, accA1, 0, 0, 0);
            accC1 = __builtin_amdgcn_mfma_f32_16x16x32_f16(a2r0, wc, accC1, 0, 0, 0);
            accB1 = __builtin_amdgcn_mfma_f32_16x16x32_f16(a1r0, wb, accB1, 0, 0, 0);
            accD1 = __builtin_amdgcn_mfma_f32_16x16x32_f16(a1r0, wd, accD1, 0, 0, 0);
            accA2 = __builtin_amdgcn_mfma_f32_16x16x32_f16(a1r1, wa, accA2, 0, 0, 0);
            accC2 = __builtin_amdgcn_mfma_f32_16x16x32_f16(a2r1, wc, accC2, 0, 0, 0);
            accB2 = __builtin_amdgcn_mfma_f32_16x16x32_f16(a1r1, wb, accB2, 0, 0, 0);
            accD2 = __builtin_amdgcn_mfma_f32_16x16x32_f16(a1r1, wd, accD2, 0, 0, 0);
        }

        // ---- epilogue ----
        #pragma unroll
        for (int r = 0; r < 4; ++r) {
            int row = kh * 4 + r;
            int nd  = node0 + row;
            if (nd < NN) {
                float o = fmaxf((accA1[r] + bA) + (accC1[r] + bC) +
                                (accB1[r] + bB) * (accD1[r] + bD), 0.f);
                h_out[nd * 64 + col] = __float2half(o);
            }
            nd += 16;
            if (nd < NN) {
                float o = fmaxf((accA2[r] + bA) + (accC2[r] + bC) +
                                (accB2[r] + bB) * (accD2[r] + bD), 0.f);
                h_out[nd * 64 + col] = __float2half(o);
            }
        }
    }
}

// ---------------- pool + MLP ----------------
__global__ __launch_bounds__(256) void pool_mlp_kernel(
    const __half* __restrict__ h, const int* __restrict__ batch,
    const float* __restrict__ w1, const float* __restrict__ b1,
    const float* __restrict__ w2, const float* __restrict__ b2,
    float* __restrict__ out)
{
    const int g = blockIdx.x;
    const int t = threadIdx.x;
    int lo = 0, hi = NN;
    while (lo < hi) { int m = (lo + hi) >> 1; if (batch[m] < g) lo = m + 1; else hi = m; }
    const int start = lo;
    hi = NN;
    while (lo < hi) { int m = (lo + hi) >> 1; if (batch[m] < g + 1) lo = m + 1; else hi = m; }
    const int end = lo;

    const int f = t & 63, wsub = t >> 6;
    float sum = 0.f;
    for (int n = start + wsub; n < end; n += 4) sum += __half2float(h[n * 64 + f]);
    __shared__ float red[4][64];
    red[wsub][f] = sum;
    __syncthreads();
    __shared__ float pooled[64];
    if (t < 64) {
        float tot = red[0][t] + red[1][t] + red[2][t] + red[3][t];
        pooled[t] = tot / fmaxf((float)(end - start), 1.f);
    }
    __syncthreads();
    __shared__ float y10[10];
    if (t < 10) {
        float acc = b1[t];
        for (int k = 0; k < 64; ++k) acc = fmaf(pooled[k], w1[k * 10 + t], acc);
        y10[t] = acc;
    }
    __syncthreads();
    if (t == 0) {
        float acc = b2[0];
        for (int j = 0; j < 10; ++j) acc = fmaf(y10[j], w2[j], acc);
        out[g] = acc;
    }
}

extern "C" void kernel_launch(void* const* d_in, const int* in_sizes, int n_in,
                              void* d_out, int out_size, void* d_ws, size_t ws_size,
                              hipStream_t stream) {
    const float* x    = (const float*)d_in[0];
    const int* ei     = (const int*)d_in[1];
    const int* batch  = (const int*)d_in[2];
    const int* src    = ei;
    const int* dstv   = ei + NE;

    // workspace layout (bytes), total ~40MB:
    //   hX16: [0, 12.8M)      hA16: [12.8M, 25.6M)
    //   csr:  [25.6M, 32.0M)  rs: [32.0M, +400004)
    //   binned: [32.5M, +7.23M)  gcur/bbase: [39.8M, +2KB)
    //   wt (12 mats fp16 transposed): [39.81M, +98304)
    char* ws     = (char*)d_ws;
    __half* hX16 = (__half*)(ws);
    __half* hA16 = (__half*)(ws + 12800000);
    int* csr     = (int*)(ws + 25600000);
    int* rs      = (int*)(ws + 32000000);
    unsigned int* binned = (unsigned int*)(ws + 32500000);
    int* gcur    = (int*)(ws + 39800000);
    int* bbase   = (int*)(ws + 39800000 + 1024);
    __half* wt   = (__half*)(ws + 39810000);

    initcur_kernel<<<1, 256, 0, stream>>>(gcur);
    binA_kernel<<<NBLK_A, 256, 0, stream>>>(src, dstv, gcur, binned);
    bscan_kernel<<<1, 256, 0, stream>>>(gcur, bbase, rs);
    binB_kernel<<<NBKT, 256, 0, stream>>>(binned, gcur, bbase, csr, rs);
    cvt_kernel<<<(NN * 64 / 4 + 255) / 256, 256, 0, stream>>>(x, hX16);

    auto f = [&](int i) { return (const float*)d_in[i]; };
    // per-layer: Wa=fc{l}1, Wc=conv{l}, Wb=fc{l}2, Wd=fc{l}3
    wprep_kernel<<<64, 256, 0, stream>>>(f(5),  f(3),  f(7),  f(9),  wt);
    wprep_kernel<<<64, 256, 0, stream>>>(f(13), f(11), f(15), f(17), wt + 16384);
    wprep_kernel<<<64, 256, 0, stream>>>(f(21), f(19), f(23), f(25), wt + 32768);

    layer_kernel<<<LAYER_GRID, 256, 0, stream>>>(hX16, hA16, csr, rs,
        wt,         f(6), f(4), f(8), f(10));
    layer_kernel<<<LAYER_GRID, 256, 0, stream>>>(hA16, hX16, csr, rs,
        wt + 16384, f(14), f(12), f(16), f(18));
    layer_kernel<<<LAYER_GRID, 256, 0, stream>>>(hX16, hA16, csr, rs,
        wt + 32768, f(22), f(20), f(24), f(26));

    pool_mlp_kernel<<<NG, 256, 0, stream>>>(hA16, batch,
        f(27), f(28), f(29), f(30), (float*)d_out);
}